// Round 11
// baseline (5138.004 us; speedup 1.0000x reference)
//
#include <hip/hip_runtime.h>
#include <hip/hip_fp16.h>

// LSTM T=512 B=64 D=256 H=256, fp32 in/out.
//
// Phase 0: X->f16; Wxt [4H][K]; Wh4 = Wh packed in MFMA B-fragment order,
//          partitioned per quarter-CU (block q owns units [64q,64q+64)).
// Phase 1: gx = X @ Wx + b via MFMA GEMM -> ws f16.
// Phase 2: recurrence with 4 CUs PER BATCH (grid 256 = all CUs; 1 block/CU
//          forced by 84KB LDS). Each CU: quarter of Wh = 128 VGPRs/wave of
//          B-fragments (fully arch-resident; no AGPR moves, no LDS/L2 weight
//          traffic - R10's structural losses). Per-step cross-CU h-exchange:
//          publish 64 f16 -> global HX[t&1], threadfence + release atomicAdd
//          on cnt[b][t] (zeroed each launch), acquire-poll to 4, gather 512B
//          via agent-scope atomic loads. Blocks of a batch grouped on one XCD
//          (blk%8 round-robin assumption; correctness independent of it).

#define T_STEPS 512
#define BATCH   64
#define HID     256
#define G4      1024
#define GM      (T_STEPS * BATCH)     // 32768

typedef _Float16 half2_t __attribute__((ext_vector_type(2)));
typedef _Float16 f16x8   __attribute__((ext_vector_type(8)));
typedef float    f32x4   __attribute__((ext_vector_type(4)));

// ws layout (f16-element offsets unless noted)
#define XH_OFF  0u          // [32768][256] f16 = 16 MB (dead after k_gemm)
#define WXT_OFF 8388608u    // [1024][256]  f16
#define WH4_OFF 8650752u    // [4][16][8][512] f16 = 512 KB (frag-ordered Wh)
#define GX_OFF  8912896u    // [32768][1024] f16
// overlaid into the dead Xh region (memset/use strictly after k_gemm):
#define HX_OFF  0u              // 2 slots x 64 x 256 f16 = 64 KB
#define CNT_BYTE_OFF 131072u    // int cnt[64*512] = 128 KB

__device__ __forceinline__ float fast_sigmoid(float x) {
    return 1.0f / (1.0f + __expf(-x));
}
__device__ __forceinline__ float fast_tanh(float x) {
    return 2.0f / (1.0f + __expf(-2.0f * x)) - 1.0f;
}

// ---------------- Phase 0a: X f32 -> f16 ----------------
__global__ __launch_bounds__(256) void k_prep_x(const float* __restrict__ X,
                                                _Float16* __restrict__ Xh) {
    const int i = blockIdx.x * 256 + threadIdx.x;
    float4 v = ((const float4*)X)[i];
    half2_t a; a.x = (_Float16)v.x; a.y = (_Float16)v.y;
    half2_t b; b.x = (_Float16)v.z; b.y = (_Float16)v.w;
    ((half2_t*)Xh)[2 * i]     = a;
    ((half2_t*)Xh)[2 * i + 1] = b;
}

// ---------------- Phase 0b: Wxt [4H][K] (gate-major cols) ----------------
__global__ __launch_bounds__(256) void k_prep_w(
    const float* __restrict__ Wax, const float* __restrict__ Wix,
    const float* __restrict__ Wfx, const float* __restrict__ Wox,
    _Float16* __restrict__ Wxt)
{
    const int id = blockIdx.x * 256 + threadIdx.x;   // [0, 262144)
    const int k  = id >> 10;
    const int c  = id & 1023;
    const int g  = c >> 8;
    const int j  = c & 255;
    const float* src = (g == 0) ? Wax : (g == 1) ? Wix : (g == 2) ? Wfx : Wox;
    Wxt[c * 256 + k] = (_Float16)src[k * 256 + j];
}

// ---------------- Phase 0c: Wh4 fragments, per-quarter unit-major ---------
// id -> (q, nt, kt, lane). Local col cl = nt*16 + (l&15) = 4*ul + g;
// unit u = 64q + ul; k = kt*32 + (l>>4)*8 + e. (B-frag layout m89-verified,
// same scheme as R10 which passed.)
__global__ __launch_bounds__(256) void k_prep_wfrag(
    const float* __restrict__ Wah, const float* __restrict__ Wih,
    const float* __restrict__ Wfh, const float* __restrict__ Woh,
    _Float16* __restrict__ Wh4)
{
    const int id = blockIdx.x * 256 + threadIdx.x;   // [0, 32768)
    const int l  = id & 63;
    const int kt = (id >> 6) & 7;
    const int nt = (id >> 9) & 15;
    const int q  = id >> 13;
    const int cl = nt * 16 + (l & 15);
    const int ul = cl >> 2;
    const int g  = cl & 3;
    const int u  = q * 64 + ul;
    const int k0 = kt * 32 + (l >> 4) * 8;
    const float* W = (g == 0) ? Wah : (g == 1) ? Wih : (g == 2) ? Wfh : Woh;
    f16x8 v;
#pragma unroll
    for (int e = 0; e < 8; ++e)
        v[e] = (_Float16)W[(size_t)(k0 + e) * 256 + u];
    *(f16x8*)(Wh4 + ((size_t)(q * 16 + nt) * 8 + kt) * 512 + l * 8) = v;
}

// ---------------- Phase 0d: zero the step counters ----------------
__global__ __launch_bounds__(256) void k_zero(int* __restrict__ p) {
    p[blockIdx.x * 256 + threadIdx.x] = 0;
}

// ---------------- Phase 1: gx = Xh @ Wxt^T + b ----------------
__global__ __launch_bounds__(256) void k_gemm(const _Float16* __restrict__ Xh,
                                              const _Float16* __restrict__ Wxt,
                                              const float* __restrict__ ba,
                                              const float* __restrict__ bi,
                                              const float* __restrict__ bf_,
                                              const float* __restrict__ bo,
                                              _Float16* __restrict__ gx)
{
    const int lane = threadIdx.x & 63, wave = threadIdx.x >> 6;
    const int rowbase = blockIdx.x * 128 + wave * 32;
    const int colbase = blockIdx.y * 64;
    const int r15 = lane & 15, kg = lane >> 4;

    f32x4 acc[2][4] = {};
    const _Float16* ap0 = Xh  + (size_t)(rowbase + r15) * 256 + kg * 8;
    const _Float16* ap1 = ap0 + 16 * 256;
    const _Float16* bp  = Wxt + (size_t)(colbase + r15) * 256 + kg * 8;

#pragma unroll
    for (int ks = 0; ks < 8; ++ks) {
        f16x8 a0 = *(const f16x8*)(ap0 + ks * 32);
        f16x8 a1 = *(const f16x8*)(ap1 + ks * 32);
        f16x8 b0 = *(const f16x8*)(bp  + ks * 32);
        f16x8 b1 = *(const f16x8*)(bp  + 16 * 256 + ks * 32);
        f16x8 b2 = *(const f16x8*)(bp  + 32 * 256 + ks * 32);
        f16x8 b3 = *(const f16x8*)(bp  + 48 * 256 + ks * 32);
        acc[0][0] = __builtin_amdgcn_mfma_f32_16x16x32_f16(a0, b0, acc[0][0], 0, 0, 0);
        acc[0][1] = __builtin_amdgcn_mfma_f32_16x16x32_f16(a0, b1, acc[0][1], 0, 0, 0);
        acc[0][2] = __builtin_amdgcn_mfma_f32_16x16x32_f16(a0, b2, acc[0][2], 0, 0, 0);
        acc[0][3] = __builtin_amdgcn_mfma_f32_16x16x32_f16(a0, b3, acc[0][3], 0, 0, 0);
        acc[1][0] = __builtin_amdgcn_mfma_f32_16x16x32_f16(a1, b0, acc[1][0], 0, 0, 0);
        acc[1][1] = __builtin_amdgcn_mfma_f32_16x16x32_f16(a1, b1, acc[1][1], 0, 0, 0);
        acc[1][2] = __builtin_amdgcn_mfma_f32_16x16x32_f16(a1, b2, acc[1][2], 0, 0, 0);
        acc[1][3] = __builtin_amdgcn_mfma_f32_16x16x32_f16(a1, b3, acc[1][3], 0, 0, 0);
    }
    float bias_n[4];
#pragma unroll
    for (int nt = 0; nt < 4; ++nt) {
        int col = colbase + nt * 16 + r15;
        bias_n[nt] = (col < 256) ? ba[col]
                   : (col < 512) ? bi[col - 256]
                   : (col < 768) ? bf_[col - 512]
                                 : bo[col - 768];
    }
#pragma unroll
    for (int mt = 0; mt < 2; ++mt)
#pragma unroll
        for (int nt = 0; nt < 4; ++nt)
#pragma unroll
            for (int r = 0; r < 4; ++r) {
                int row = rowbase + mt * 16 + kg * 4 + r;
                int col = colbase + nt * 16 + r15;
                gx[(size_t)row * G4 + col] = (_Float16)(acc[mt][nt][r] + bias_n[nt]);
            }
}

// ---------------- Phase 2: cross-CU MFMA recurrence ----------------

#define MFMA16(a, bfr, acc) __builtin_amdgcn_mfma_f32_16x16x32_f16(a, bfr, acc, 0, 0, 0)
#define LW(n, k) (*(const f16x8*)(Wb + ((n) * 8 + (k)) * 512))
#define KT(k)                          \
    c0 = MFMA16(a##k, w0##k, c0);      \
    c1 = MFMA16(a##k, w1##k, c1);      \
    c2 = MFMA16(a##k, w2##k, c2);      \
    c3 = MFMA16(a##k, w3##k, c3);

__global__ void __launch_bounds__(256, 1)
__attribute__((amdgpu_waves_per_eu(1, 1)))
k_recur(const _Float16* __restrict__ Wh4, const _Float16* __restrict__ gx,
        _Float16* __restrict__ HX, int* __restrict__ cnt,
        float* __restrict__ out)
{
    const int blk  = blockIdx.x;
    const int x    = blk & 7;           // XCD (assuming blk%8 round-robin)
    const int m    = blk >> 3;
    const int q    = m & 3;             // quarter: units [64q, 64q+64)
    const int b    = (m >> 2) * 8 + x;  // batch

    const int tid  = threadIdx.x;
    const int lane = tid & 63;
    const int w    = tid >> 6;

    // 84 KB LDS forces 1 block/CU -> all 256 blocks co-resident (no deadlock).
    __shared__ __align__(16) char lds_all[86016];
    _Float16* hbuf = (_Float16*)lds_all;          // 512 B: h_{t-1}
    float*    act  = (float*)(lds_all + 1024);    // 1 KB: gate pre-activations

    // ---- B-fragments: wave w owns local nt w*4..w*4+3, 8 kt each ----
    const _Float16* Wb = Wh4 + ((size_t)(q * 16 + w * 4) * 8) * 512 + lane * 8;
    f16x8 w00 = LW(0,0), w01 = LW(0,1), w02 = LW(0,2), w03 = LW(0,3),
          w04 = LW(0,4), w05 = LW(0,5), w06 = LW(0,6), w07 = LW(0,7);
    f16x8 w10 = LW(1,0), w11 = LW(1,1), w12 = LW(1,2), w13 = LW(1,3),
          w14 = LW(1,4), w15 = LW(1,5), w16 = LW(1,6), w17 = LW(1,7);
    f16x8 w20 = LW(2,0), w21 = LW(2,1), w22 = LW(2,2), w23 = LW(2,3),
          w24 = LW(2,4), w25 = LW(2,5), w26 = LW(2,6), w27 = LW(2,7);
    f16x8 w30 = LW(3,0), w31 = LW(3,1), w32 = LW(3,2), w33 = LW(3,3),
          w34 = LW(3,4), w35 = LW(3,5), w36 = LW(3,6), w37 = LW(3,7);

    hbuf[tid] = (_Float16)0.0f;
    float s = 0.0f;
    const int u = q * 64 + tid;        // global unit (valid for tid < 64)
    _Float16 gc0 = (_Float16)0.f, gc1 = (_Float16)0.f;
    _Float16 gc2 = (_Float16)0.f, gc3 = (_Float16)0.f;
    if (tid < 64) {
        const size_t r0 = (size_t)b * G4;
        gc0 = gx[r0 + u];       gc1 = gx[r0 + 256 + u];
        gc2 = gx[r0 + 512 + u]; gc3 = gx[r0 + 768 + u];
    }
    __syncthreads();

#pragma unroll 1
    for (int t = 0; t < T_STEPS; ++t) {
        // prefetch next-step gx (wave0 only; covers latency under MFMA+sync)
        _Float16 gn0 = (_Float16)0.f, gn1 = (_Float16)0.f;
        _Float16 gn2 = (_Float16)0.f, gn3 = (_Float16)0.f;
        if (tid < 64 && t + 1 < T_STEPS) {
            const size_t r = ((size_t)(t + 1) * BATCH + b) * G4;
            gn0 = gx[r + u];       gn1 = gx[r + 256 + u];
            gn2 = gx[r + 512 + u]; gn3 = gx[r + 768 + u];
        }

        // ---- A-fragments: h broadcast (all 16 M-rows = h) ----
        const _Float16* hap = hbuf + (lane >> 4) * 8;
        f16x8 a0 = *(const f16x8*)(hap + 0);
        f16x8 a1 = *(const f16x8*)(hap + 32);
        f16x8 a2 = *(const f16x8*)(hap + 64);
        f16x8 a3 = *(const f16x8*)(hap + 96);
        f16x8 a4 = *(const f16x8*)(hap + 128);
        f16x8 a5 = *(const f16x8*)(hap + 160);
        f16x8 a6 = *(const f16x8*)(hap + 192);
        f16x8 a7 = *(const f16x8*)(hap + 224);

        f32x4 c0 = {0.f, 0.f, 0.f, 0.f}, c1 = {0.f, 0.f, 0.f, 0.f};
        f32x4 c2 = {0.f, 0.f, 0.f, 0.f}, c3 = {0.f, 0.f, 0.f, 0.f};
        KT(0) KT(1) KT(2) KT(3) KT(4) KT(5) KT(6) KT(7)

        // row 0 of C = result (lanes 0..15, reg 0)
        if (lane < 16) {
            act[(w * 4 + 0) * 16 + lane] = c0[0];
            act[(w * 4 + 1) * 16 + lane] = c1[0];
            act[(w * 4 + 2) * 16 + lane] = c2[0];
            act[(w * 4 + 3) * 16 + lane] = c3[0];
        }
        __syncthreads();   // act ready; hbuf reads done

        // ---- epilogue + publish (wave 0 only; wave-uniform branch) ----
        if (tid < 64) {
            float4 g4v = ((const float4*)act)[tid];   // a,i,f,o of unit u
            float gA = g4v.x + (float)gc0;
            float gB = g4v.y + (float)gc1;
            float gC = g4v.z + (float)gc2;
            float gD = g4v.w + (float)gc3;
            float aa = fast_tanh(gA);
            float ii = fast_sigmoid(gB);
            float ff = fast_sigmoid(gC);
            float oo = fast_sigmoid(gD);
            s = aa * ii + s * ff;
            float h = fast_tanh(s) * oo;
            out[((size_t)t * BATCH + b) * HID + u] = h;
            HX[(size_t)(t & 1) * 16384 + b * 256 + u] = (_Float16)h;
            __threadfence();                      // device-scope: h visible
            if (tid == 0)
                __hip_atomic_fetch_add(&cnt[b * T_STEPS + t], 1,
                                       __ATOMIC_RELEASE,
                                       __HIP_MEMORY_SCOPE_AGENT);
        }
        // ---- wait for all 4 quarters of this batch ----
        if (tid == 0) {
            int* cp = &cnt[b * T_STEPS + t];
            int spins = 0;
            while (__hip_atomic_load(cp, __ATOMIC_ACQUIRE,
                                     __HIP_MEMORY_SCOPE_AGENT) < 4) {
                __builtin_amdgcn_s_sleep(2);
                if (++spins > 50000) break;       // bounded: fail, don't hang
            }
        }
        __syncthreads();
        // ---- gather full h (512 B) with L1-bypassing loads ----
        if (tid < 128) {
            const unsigned* src =
                (const unsigned*)(HX + (size_t)(t & 1) * 16384) + b * 128 + tid;
            ((unsigned*)hbuf)[tid] =
                __hip_atomic_load(src, __ATOMIC_RELAXED,
                                  __HIP_MEMORY_SCOPE_AGENT);
        }
        gc0 = gn0; gc1 = gn1; gc2 = gn2; gc3 = gn3;
        __syncthreads();   // hbuf ready for next step
    }
}

extern "C" void kernel_launch(void* const* d_in, const int* in_sizes, int n_in,
                              void* d_out, int out_size, void* d_ws, size_t ws_size,
                              hipStream_t stream) {
    const float* X   = (const float*)d_in[0];
    const float* Wax = (const float*)d_in[1];
    const float* Wix = (const float*)d_in[2];
    const float* Wfx = (const float*)d_in[3];
    const float* Wox = (const float*)d_in[4];
    const float* Wah = (const float*)d_in[5];
    const float* Wih = (const float*)d_in[6];
    const float* Wfh = (const float*)d_in[7];
    const float* Woh = (const float*)d_in[8];
    const float* ba  = (const float*)d_in[9];
    const float* bi  = (const float*)d_in[10];
    const float* bf  = (const float*)d_in[11];
    const float* bo  = (const float*)d_in[12];

    _Float16* ws  = (_Float16*)d_ws;
    _Float16* Xh  = ws + XH_OFF;
    _Float16* Wxt = ws + WXT_OFF;
    _Float16* Wh4 = ws + WH4_OFF;
    _Float16* gxp = ws + GX_OFF;
    _Float16* HX  = ws + HX_OFF;                        // overlaid in Xh region
    int*      cnt = (int*)((char*)d_ws + CNT_BYTE_OFF); // overlaid in Xh region

    k_prep_x<<<dim3(GM * 256 / 4 / 256), dim3(256), 0, stream>>>(X, Xh);
    k_prep_w<<<dim3(1024), dim3(256), 0, stream>>>(Wax, Wix, Wfx, Wox, Wxt);
    k_prep_wfrag<<<dim3(128), dim3(256), 0, stream>>>(Wah, Wih, Wfh, Woh, Wh4);
    k_gemm<<<dim3(GM / 128, G4 / 64), dim3(256), 0, stream>>>(
        Xh, Wxt, ba, bi, bf, bo, gxp);
    k_zero<<<dim3(128), dim3(256), 0, stream>>>(cnt);   // after k_gemm: Xh dead
    k_recur<<<dim3(256), dim3(256), 0, stream>>>(Wh4, gxp, HX, cnt,
                                                 (float*)d_out);
}

// Round 13
// 1026.951 us; speedup vs baseline: 5.0032x; 5.0032x over previous
//
#include <hip/hip_runtime.h>
#include <hip/hip_fp16.h>

// LSTM T=512 B=64 D=256 H=256, fp32 in/out.
//
// Phase 0: X->f16; Wxt [4H][K] f16; Wh8 = Wh*64 quantized to fp8 e4m3 and
//          packed in MFMA B-fragment order, unit-major columns (c=4u+g).
// Phase 1: gx = X @ Wx + b via f16 MFMA GEMM -> ws f16.
// Phase 2: recurrence, 1 CU/batch, 256 thr (4 waves, 1/SIMD, 512 unified regs).
//          gates = (16h)@(64Wh)/1024 via mfma_f32_16x16x32_fp8_fp8.
//          Wave owns 16 N-tiles x 8 K-tiles: B-frags = 128 longs = 256 regs,
//          FULLY register-resident (fp8 halves Wh to 256KB = AGPR capacity;
//          MFMA reads B from AGPR natively - kills R9's VALU-move tax and
//          R10's LDS/L2 weight streaming). A = h broadcast (fp8, x16 scale);
//          all C rows equal -> row 0 = result. act via same-wave LDS,
//          epilogue on all 64 lanes/wave, ONE barrier/step.
//          (R12 fix: cvt_pk_fp8 'hi' operand must be a literal -> template.)

#define T_STEPS 512
#define BATCH   64
#define HID     256
#define G4      1024
#define GM      (T_STEPS * BATCH)     // 32768

typedef _Float16 half2_t __attribute__((ext_vector_type(2)));
typedef _Float16 f16x8   __attribute__((ext_vector_type(8)));
typedef float    f32x4   __attribute__((ext_vector_type(4)));

// ws layout
#define XH_OFF  0u          // f16[32768][256]
#define WXT_OFF 8388608u    // f16[1024][256]
#define GX_OFF  8912896u    // f16[32768][1024]
#define WH8_BYTE_OFF (8650752u * 2u)   // 256 KB fp8 frag-packed Wh (in old gap)

__device__ __forceinline__ float fast_sigmoid(float x) {
    return 1.0f / (1.0f + __expf(-x));
}
__device__ __forceinline__ float fast_tanh(float x) {
    return 2.0f / (1.0f + __expf(-2.0f * x)) - 1.0f;
}

// ---- fp8 e4m3fn encode (RN; flush |x|<2^-6 to 0; clamp to 448) ----
__device__ __forceinline__ unsigned char sw_e4m3(float x) {
    unsigned u = __float_as_uint(x);
    unsigned s = (u >> 24) & 0x80u;
    int e = (int)((u >> 23) & 0xffu) - 127;
    unsigned m = u & 0x7fffffu;
    if (e < -6) return (unsigned char)s;
    m += 0x00080000u;                       // round half up at 3-bit mantissa
    if (m & 0x800000u) { m = 0; e += 1; }
    int E = e + 7;
    if (E > 15 || (E == 15 && (m >> 20) > 6)) { E = 15; m = 6u << 20; }
    return (unsigned char)(s | ((unsigned)E << 3) | (m >> 20));
}
template <bool HI>
__device__ __forceinline__ unsigned cvt2_fp8(float a, float b, unsigned old) {
#if __has_builtin(__builtin_amdgcn_cvt_pk_fp8_f32)
    return (unsigned)__builtin_amdgcn_cvt_pk_fp8_f32(a, b, (int)old, HI);
#else
    unsigned lo16 = (unsigned)sw_e4m3(a) | ((unsigned)sw_e4m3(b) << 8);
    return HI ? ((old & 0xFFFFu) | (lo16 << 16))
              : ((old & 0xFFFF0000u) | lo16);
#endif
}

// ---------------- Phase 0a: X f32 -> f16 ----------------
__global__ __launch_bounds__(256) void k_prep_x(const float* __restrict__ X,
                                                _Float16* __restrict__ Xh) {
    const int i = blockIdx.x * 256 + threadIdx.x;
    float4 v = ((const float4*)X)[i];
    half2_t a; a.x = (_Float16)v.x; a.y = (_Float16)v.y;
    half2_t b; b.x = (_Float16)v.z; b.y = (_Float16)v.w;
    ((half2_t*)Xh)[2 * i]     = a;
    ((half2_t*)Xh)[2 * i + 1] = b;
}

// ---------------- Phase 0b: Wxt [4H][K] (gate-major cols) ----------------
__global__ __launch_bounds__(256) void k_prep_w(
    const float* __restrict__ Wax, const float* __restrict__ Wix,
    const float* __restrict__ Wfx, const float* __restrict__ Wox,
    _Float16* __restrict__ Wxt)
{
    const int id = blockIdx.x * 256 + threadIdx.x;
    const int k  = id >> 10;
    const int c  = id & 1023;
    const int g  = c >> 8;
    const int j  = c & 255;
    const float* src = (g == 0) ? Wax : (g == 1) ? Wix : (g == 2) ? Wfx : Wox;
    Wxt[c * 256 + k] = (_Float16)src[k * 256 + j];
}

// ---------------- Phase 0c: Wh8 fp8 fragments, unit-major cols -----------
// id -> (ntG in [0,64), kt in [0,8), lane). col c = ntG*16 + (l&15) = 4u+g;
// k = kt*32 + (l>>4)*8 + e. Stores 8 bytes (e=0..7) of W[k][u]*64 as e4m3.
__global__ __launch_bounds__(256) void k_prep_wfrag8(
    const float* __restrict__ Wah, const float* __restrict__ Wih,
    const float* __restrict__ Wfh, const float* __restrict__ Woh,
    unsigned char* __restrict__ Wh8)
{
    const int id  = blockIdx.x * 256 + threadIdx.x;   // [0, 32768)
    const int l   = id & 63;
    const int kt  = (id >> 6) & 7;
    const int ntG = id >> 9;
    const int c   = ntG * 16 + (l & 15);
    const int u   = c >> 2;
    const int g   = c & 3;
    const int k0  = kt * 32 + (l >> 4) * 8;
    const float* W = (g == 0) ? Wah : (g == 1) ? Wih : (g == 2) ? Wfh : Woh;
    float v[8];
#pragma unroll
    for (int e = 0; e < 8; ++e)
        v[e] = W[(size_t)(k0 + e) * 256 + u] * 64.0f;
    unsigned lo = cvt2_fp8<false>(v[0], v[1], 0u);
    lo = cvt2_fp8<true>(v[2], v[3], lo);
    unsigned hi = cvt2_fp8<false>(v[4], v[5], 0u);
    hi = cvt2_fp8<true>(v[6], v[7], hi);
    uint2 pk; pk.x = lo; pk.y = hi;
    *(uint2*)(Wh8 + ((size_t)(ntG * 8 + kt) * 64 + l) * 8) = pk;
}

// ---------------- Phase 1: gx = Xh @ Wxt^T + b ----------------
__global__ __launch_bounds__(256) void k_gemm(const _Float16* __restrict__ Xh,
                                              const _Float16* __restrict__ Wxt,
                                              const float* __restrict__ ba,
                                              const float* __restrict__ bi,
                                              const float* __restrict__ bf_,
                                              const float* __restrict__ bo,
                                              _Float16* __restrict__ gx)
{
    const int lane = threadIdx.x & 63, wave = threadIdx.x >> 6;
    const int rowbase = blockIdx.x * 128 + wave * 32;
    const int colbase = blockIdx.y * 64;
    const int r15 = lane & 15, kg = lane >> 4;

    f32x4 acc[2][4] = {};
    const _Float16* ap0 = Xh  + (size_t)(rowbase + r15) * 256 + kg * 8;
    const _Float16* ap1 = ap0 + 16 * 256;
    const _Float16* bp  = Wxt + (size_t)(colbase + r15) * 256 + kg * 8;

#pragma unroll
    for (int ks = 0; ks < 8; ++ks) {
        f16x8 a0 = *(const f16x8*)(ap0 + ks * 32);
        f16x8 a1 = *(const f16x8*)(ap1 + ks * 32);
        f16x8 b0 = *(const f16x8*)(bp  + ks * 32);
        f16x8 b1 = *(const f16x8*)(bp  + 16 * 256 + ks * 32);
        f16x8 b2 = *(const f16x8*)(bp  + 32 * 256 + ks * 32);
        f16x8 b3 = *(const f16x8*)(bp  + 48 * 256 + ks * 32);
        acc[0][0] = __builtin_amdgcn_mfma_f32_16x16x32_f16(a0, b0, acc[0][0], 0, 0, 0);
        acc[0][1] = __builtin_amdgcn_mfma_f32_16x16x32_f16(a0, b1, acc[0][1], 0, 0, 0);
        acc[0][2] = __builtin_amdgcn_mfma_f32_16x16x32_f16(a0, b2, acc[0][2], 0, 0, 0);
        acc[0][3] = __builtin_amdgcn_mfma_f32_16x16x32_f16(a0, b3, acc[0][3], 0, 0, 0);
        acc[1][0] = __builtin_amdgcn_mfma_f32_16x16x32_f16(a1, b0, acc[1][0], 0, 0, 0);
        acc[1][1] = __builtin_amdgcn_mfma_f32_16x16x32_f16(a1, b1, acc[1][1], 0, 0, 0);
        acc[1][2] = __builtin_amdgcn_mfma_f32_16x16x32_f16(a1, b2, acc[1][2], 0, 0, 0);
        acc[1][3] = __builtin_amdgcn_mfma_f32_16x16x32_f16(a1, b3, acc[1][3], 0, 0, 0);
    }
    float bias_n[4];
#pragma unroll
    for (int nt = 0; nt < 4; ++nt) {
        int col = colbase + nt * 16 + r15;
        bias_n[nt] = (col < 256) ? ba[col]
                   : (col < 512) ? bi[col - 256]
                   : (col < 768) ? bf_[col - 512]
                                 : bo[col - 768];
    }
#pragma unroll
    for (int mt = 0; mt < 2; ++mt)
#pragma unroll
        for (int nt = 0; nt < 4; ++nt)
#pragma unroll
            for (int r = 0; r < 4; ++r) {
                int row = rowbase + mt * 16 + kg * 4 + r;
                int col = colbase + nt * 16 + r15;
                gx[(size_t)row * G4 + col] = (_Float16)(acc[mt][nt][r] + bias_n[nt]);
            }
}

// ---------------- Phase 2: fp8 MFMA recurrence ----------------

#define M8(a, bfr, acc) \
    __builtin_amdgcn_mfma_f32_16x16x32_fp8_fp8((a), (bfr), (acc), 0, 0, 0)
#define WB(n, k) (*(const long*)(Wp + ((size_t)((n) * 8 + (k)) * 64) * 8))

#define DB(n)                                                                  \
    long b##n##_0 = WB(n,0), b##n##_1 = WB(n,1), b##n##_2 = WB(n,2),           \
         b##n##_3 = WB(n,3), b##n##_4 = WB(n,4), b##n##_5 = WB(n,5),           \
         b##n##_6 = WB(n,6), b##n##_7 = WB(n,7);

#define TILE(n)                                                                \
    {                                                                          \
        f32x4 acc = {0.f, 0.f, 0.f, 0.f};                                      \
        acc = M8(a0, b##n##_0, acc); acc = M8(a1, b##n##_1, acc);              \
        acc = M8(a2, b##n##_2, acc); acc = M8(a3, b##n##_3, acc);              \
        acc = M8(a4, b##n##_4, acc); acc = M8(a5, b##n##_5, acc);              \
        acc = M8(a6, b##n##_6, acc); acc = M8(a7, b##n##_7, acc);              \
        if (lane < 16) actw[(n) * 16 + lane] = acc[0];                         \
    }

__global__ void __launch_bounds__(256, 1)
__attribute__((amdgpu_waves_per_eu(1, 1)))
k_recur(const unsigned char* __restrict__ Wh8, const _Float16* __restrict__ gx,
        float* __restrict__ out)
{
    const int b    = blockIdx.x;
    const int tid  = threadIdx.x;      // 0..255
    const int lane = tid & 63;
    const int w    = tid >> 6;         // wave: cols [256w, +256), units [64w,+64)

    __shared__ __align__(16) float act[1024];          // 4 KB, per-wave 256
    __shared__ __align__(8)  unsigned char hbufs[2][256];

    float* actw = act + w * 256;
    // wave's B-frag base: global ntile = w*16 + n
    const unsigned char* Wp = Wh8 + ((size_t)(w * 16) * 8 * 64) * 8 + lane * 8;

    // ---- 128 register-resident fp8 B-fragments (256 regs) ----
    DB(0)  DB(1)  DB(2)  DB(3)  DB(4)  DB(5)  DB(6)  DB(7)
    DB(8)  DB(9)  DB(10) DB(11) DB(12) DB(13) DB(14) DB(15)

    hbufs[0][tid] = 0;                 // h0 = 0 (fp8 zero = 0x00)
    float s = 0.0f;
    const int u = w * 64 + lane;       // this thread's unit
    _Float16 gc0 = gx[(size_t)b * G4 + u];
    _Float16 gc1 = gx[(size_t)b * G4 + 256 + u];
    _Float16 gc2 = gx[(size_t)b * G4 + 512 + u];
    _Float16 gc3 = gx[(size_t)b * G4 + 768 + u];
    __syncthreads();

#pragma unroll 1
    for (int t = 0; t < T_STEPS; ++t) {
        // prefetch next-step gx
        _Float16 gn0 = (_Float16)0.f, gn1 = (_Float16)0.f;
        _Float16 gn2 = (_Float16)0.f, gn3 = (_Float16)0.f;
        if (t + 1 < T_STEPS) {
            const size_t r = ((size_t)(t + 1) * BATCH + b) * G4;
            gn0 = gx[r + u];       gn1 = gx[r + 256 + u];
            gn2 = gx[r + 512 + u]; gn3 = gx[r + 768 + u];
        }

        // ---- A-fragments: fp8 h broadcast; lane's 8 bytes at k-subchunk ----
        const unsigned char* hb = &hbufs[t & 1][0] + ((lane >> 4) * 8);
        long a0 = *(const long*)(hb + 0);
        long a1 = *(const long*)(hb + 32);
        long a2 = *(const long*)(hb + 64);
        long a3 = *(const long*)(hb + 96);
        long a4 = *(const long*)(hb + 128);
        long a5 = *(const long*)(hb + 160);
        long a6 = *(const long*)(hb + 192);
        long a7 = *(const long*)(hb + 224);

        TILE(0)  TILE(1)  TILE(2)  TILE(3)
        TILE(4)  TILE(5)  TILE(6)  TILE(7)
        TILE(8)  TILE(9)  TILE(10) TILE(11)
        TILE(12) TILE(13) TILE(14) TILE(15)

        asm volatile("s_waitcnt lgkmcnt(0)" ::: "memory");  // act stores done

        // ---- epilogue: all 64 lanes/wave; unit u = 64w + lane ----
        {
            float4 g4v = ((const float4*)act)[w * 64 + lane];  // a,i,f,o raw
            const float S = 0.0009765625f;                     // 2^-10
            float gA = g4v.x * S + (float)gc0;
            float gB = g4v.y * S + (float)gc1;
            float gC = g4v.z * S + (float)gc2;
            float gD = g4v.w * S + (float)gc3;
            float aa = fast_tanh(gA);
            float ii = fast_sigmoid(gB);
            float ff = fast_sigmoid(gC);
            float oo = fast_sigmoid(gD);
            s = aa * ii + s * ff;
            float h = fast_tanh(s) * oo;
            out[((size_t)t * BATCH + b) * HID + u] = h;
            // publish h*16 as fp8 into the other slot
            unsigned p8 = cvt2_fp8<false>(h * 16.0f, h * 16.0f, 0u);
            hbufs[(t + 1) & 1][u] = (unsigned char)(p8 & 0xffu);
        }
        gc0 = gn0; gc1 = gn1; gc2 = gn2; gc3 = gn3;
        __syncthreads();   // next slot complete before t+1 A-reads
    }
}

extern "C" void kernel_launch(void* const* d_in, const int* in_sizes, int n_in,
                              void* d_out, int out_size, void* d_ws, size_t ws_size,
                              hipStream_t stream) {
    const float* X   = (const float*)d_in[0];
    const float* Wax = (const float*)d_in[1];
    const float* Wix = (const float*)d_in[2];
    const float* Wfx = (const float*)d_in[3];
    const float* Wox = (const float*)d_in[4];
    const float* Wah = (const float*)d_in[5];
    const float* Wih = (const float*)d_in[6];
    const float* Wfh = (const float*)d_in[7];
    const float* Woh = (const float*)d_in[8];
    const float* ba  = (const float*)d_in[9];
    const float* bi  = (const float*)d_in[10];
    const float* bf  = (const float*)d_in[11];
    const float* bo  = (const float*)d_in[12];

    _Float16* ws  = (_Float16*)d_ws;
    _Float16* Xh  = ws + XH_OFF;
    _Float16* Wxt = ws + WXT_OFF;
    _Float16* gxp = ws + GX_OFF;
    unsigned char* Wh8 = (unsigned char*)d_ws + WH8_BYTE_OFF;

    k_prep_x<<<dim3(GM * 256 / 4 / 256), dim3(256), 0, stream>>>(X, Xh);
    k_prep_w<<<dim3(1024), dim3(256), 0, stream>>>(Wax, Wix, Wfx, Wox, Wxt);
    k_prep_wfrag8<<<dim3(128), dim3(256), 0, stream>>>(Wah, Wih, Wfh, Woh, Wh8);
    k_gemm<<<dim3(GM / 128, G4 / 64), dim3(256), 0, stream>>>(
        Xh, Wxt, ba, bi, bf, bo, gxp);
    k_recur<<<dim3(BATCH), dim3(256), 0, stream>>>(Wh8, gxp, (float*)d_out);
}

// Round 14
// 929.409 us; speedup vs baseline: 5.5282x; 1.1050x over previous
//
#include <hip/hip_runtime.h>
#include <hip/hip_fp16.h>

// LSTM T=512 B=64 D=256 H=256, fp32 in/out.
//
// Phase 0: X->f16; Wxt [4H][K] f16; Wh8 = Wh*64 quantized to fp8 e4m3 and
//          packed in MFMA B-fragment order, unit-major columns (c=4u+g).
// Phase 1: gx = X @ Wx + b via f16 MFMA GEMM -> ws f16 (UNIT-MAJOR cols:
//          stored at 4j+g so k_recur reads one uint2 per unit per step).
// Phase 2: recurrence, 1 CU/batch, 256 thr (4 waves, 1/SIMD, 512 unified regs).
//          gates = (16h)@(64Wh)/1024 via mfma_f32_16x16x32_fp8_fp8.
//          B-frags = 128 longs = 256 regs, fully register-resident.
//          R13 fix: MFMAs issued K-MAJOR (16 independent tiles per k-step,
//          dependency distance 16 issues) - R13's tile-major order serialized
//          16 x 8-deep dependent chains (~4100 cyc, measured 4340). Single
//          store block after all MFMAs (one exec toggle).

#define T_STEPS 512
#define BATCH   64
#define HID     256
#define G4      1024
#define GM      (T_STEPS * BATCH)     // 32768

typedef _Float16 half2_t __attribute__((ext_vector_type(2)));
typedef _Float16 f16x8   __attribute__((ext_vector_type(8)));
typedef float    f32x4   __attribute__((ext_vector_type(4)));

// ws layout
#define XH_OFF  0u          // f16[32768][256]
#define WXT_OFF 8388608u    // f16[1024][256]
#define GX_OFF  8912896u    // f16[32768][1024]
#define WH8_BYTE_OFF (8650752u * 2u)   // 256 KB fp8 frag-packed Wh

__device__ __forceinline__ float fast_sigmoid(float x) {
    return 1.0f / (1.0f + __expf(-x));
}
__device__ __forceinline__ float fast_tanh(float x) {
    return 2.0f / (1.0f + __expf(-2.0f * x)) - 1.0f;
}

// ---- fp8 e4m3fn encode (RN; flush |x|<2^-6 to 0; clamp to 448) ----
__device__ __forceinline__ unsigned char sw_e4m3(float x) {
    unsigned u = __float_as_uint(x);
    unsigned s = (u >> 24) & 0x80u;
    int e = (int)((u >> 23) & 0xffu) - 127;
    unsigned m = u & 0x7fffffu;
    if (e < -6) return (unsigned char)s;
    m += 0x00080000u;
    if (m & 0x800000u) { m = 0; e += 1; }
    int E = e + 7;
    if (E > 15 || (E == 15 && (m >> 20) > 6)) { E = 15; m = 6u << 20; }
    return (unsigned char)(s | ((unsigned)E << 3) | (m >> 20));
}
template <bool HI>
__device__ __forceinline__ unsigned cvt2_fp8(float a, float b, unsigned old) {
#if __has_builtin(__builtin_amdgcn_cvt_pk_fp8_f32)
    return (unsigned)__builtin_amdgcn_cvt_pk_fp8_f32(a, b, (int)old, HI);
#else
    unsigned lo16 = (unsigned)sw_e4m3(a) | ((unsigned)sw_e4m3(b) << 8);
    return HI ? ((old & 0xFFFFu) | (lo16 << 16))
              : ((old & 0xFFFF0000u) | lo16);
#endif
}

// ---------------- Phase 0a: X f32 -> f16 ----------------
__global__ __launch_bounds__(256) void k_prep_x(const float* __restrict__ X,
                                                _Float16* __restrict__ Xh) {
    const int i = blockIdx.x * 256 + threadIdx.x;
    float4 v = ((const float4*)X)[i];
    half2_t a; a.x = (_Float16)v.x; a.y = (_Float16)v.y;
    half2_t b; b.x = (_Float16)v.z; b.y = (_Float16)v.w;
    ((half2_t*)Xh)[2 * i]     = a;
    ((half2_t*)Xh)[2 * i + 1] = b;
}

// ---------------- Phase 0b: Wxt [4H][K] (gate-major cols) ----------------
__global__ __launch_bounds__(256) void k_prep_w(
    const float* __restrict__ Wax, const float* __restrict__ Wix,
    const float* __restrict__ Wfx, const float* __restrict__ Wox,
    _Float16* __restrict__ Wxt)
{
    const int id = blockIdx.x * 256 + threadIdx.x;
    const int k  = id >> 10;
    const int c  = id & 1023;
    const int g  = c >> 8;
    const int j  = c & 255;
    const float* src = (g == 0) ? Wax : (g == 1) ? Wix : (g == 2) ? Wfx : Wox;
    Wxt[c * 256 + k] = (_Float16)src[k * 256 + j];
}

// ---------------- Phase 0c: Wh8 fp8 fragments, unit-major cols -----------
__global__ __launch_bounds__(256) void k_prep_wfrag8(
    const float* __restrict__ Wah, const float* __restrict__ Wih,
    const float* __restrict__ Wfh, const float* __restrict__ Woh,
    unsigned char* __restrict__ Wh8)
{
    const int id  = blockIdx.x * 256 + threadIdx.x;   // [0, 32768)
    const int l   = id & 63;
    const int kt  = (id >> 6) & 7;
    const int ntG = id >> 9;
    const int c   = ntG * 16 + (l & 15);
    const int u   = c >> 2;
    const int g   = c & 3;
    const int k0  = kt * 32 + (l >> 4) * 8;
    const float* W = (g == 0) ? Wah : (g == 1) ? Wih : (g == 2) ? Wfh : Woh;
    float v[8];
#pragma unroll
    for (int e = 0; e < 8; ++e)
        v[e] = W[(size_t)(k0 + e) * 256 + u] * 64.0f;
    unsigned lo = cvt2_fp8<false>(v[0], v[1], 0u);
    lo = cvt2_fp8<true>(v[2], v[3], lo);
    unsigned hi = cvt2_fp8<false>(v[4], v[5], 0u);
    hi = cvt2_fp8<true>(v[6], v[7], hi);
    uint2 pk; pk.x = lo; pk.y = hi;
    *(uint2*)(Wh8 + ((size_t)(ntG * 8 + kt) * 64 + l) * 8) = pk;
}

// ---------------- Phase 1: gx = Xh @ Wxt^T + b (unit-major store) --------
__global__ __launch_bounds__(256) void k_gemm(const _Float16* __restrict__ Xh,
                                              const _Float16* __restrict__ Wxt,
                                              const float* __restrict__ ba,
                                              const float* __restrict__ bi,
                                              const float* __restrict__ bf_,
                                              const float* __restrict__ bo,
                                              _Float16* __restrict__ gx)
{
    const int lane = threadIdx.x & 63, wave = threadIdx.x >> 6;
    const int rowbase = blockIdx.x * 128 + wave * 32;
    const int colbase = blockIdx.y * 64;
    const int r15 = lane & 15, kg = lane >> 4;

    f32x4 acc[2][4] = {};
    const _Float16* ap0 = Xh  + (size_t)(rowbase + r15) * 256 + kg * 8;
    const _Float16* ap1 = ap0 + 16 * 256;
    const _Float16* bp  = Wxt + (size_t)(colbase + r15) * 256 + kg * 8;

#pragma unroll
    for (int ks = 0; ks < 8; ++ks) {
        f16x8 a0 = *(const f16x8*)(ap0 + ks * 32);
        f16x8 a1 = *(const f16x8*)(ap1 + ks * 32);
        f16x8 b0 = *(const f16x8*)(bp  + ks * 32);
        f16x8 b1 = *(const f16x8*)(bp  + 16 * 256 + ks * 32);
        f16x8 b2 = *(const f16x8*)(bp  + 32 * 256 + ks * 32);
        f16x8 b3 = *(const f16x8*)(bp  + 48 * 256 + ks * 32);
        acc[0][0] = __builtin_amdgcn_mfma_f32_16x16x32_f16(a0, b0, acc[0][0], 0, 0, 0);
        acc[0][1] = __builtin_amdgcn_mfma_f32_16x16x32_f16(a0, b1, acc[0][1], 0, 0, 0);
        acc[0][2] = __builtin_amdgcn_mfma_f32_16x16x32_f16(a0, b2, acc[0][2], 0, 0, 0);
        acc[0][3] = __builtin_amdgcn_mfma_f32_16x16x32_f16(a0, b3, acc[0][3], 0, 0, 0);
        acc[1][0] = __builtin_amdgcn_mfma_f32_16x16x32_f16(a1, b0, acc[1][0], 0, 0, 0);
        acc[1][1] = __builtin_amdgcn_mfma_f32_16x16x32_f16(a1, b1, acc[1][1], 0, 0, 0);
        acc[1][2] = __builtin_amdgcn_mfma_f32_16x16x32_f16(a1, b2, acc[1][2], 0, 0, 0);
        acc[1][3] = __builtin_amdgcn_mfma_f32_16x16x32_f16(a1, b3, acc[1][3], 0, 0, 0);
    }
    float bias_n[4];
#pragma unroll
    for (int nt = 0; nt < 4; ++nt) {
        int col = colbase + nt * 16 + r15;
        bias_n[nt] = (col < 256) ? ba[col]
                   : (col < 512) ? bi[col - 256]
                   : (col < 768) ? bf_[col - 512]
                                 : bo[col - 768];
    }
    // unit-major permuted store: col (= g*256+j) -> 4*j + g
#pragma unroll
    for (int mt = 0; mt < 2; ++mt)
#pragma unroll
        for (int nt = 0; nt < 4; ++nt)
#pragma unroll
            for (int r = 0; r < 4; ++r) {
                int row = rowbase + mt * 16 + kg * 4 + r;
                int col = colbase + nt * 16 + r15;
                int g   = col >> 8, j = col & 255;
                gx[(size_t)row * G4 + 4 * j + g] =
                    (_Float16)(acc[mt][nt][r] + bias_n[nt]);
            }
}

// ---------------- Phase 2: fp8 MFMA recurrence (k-major interleave) ------

#define M8(a, bfr, acc) \
    __builtin_amdgcn_mfma_f32_16x16x32_fp8_fp8((a), (bfr), (acc), 0, 0, 0)
#define WB(n, k) (*(const long*)(Wp + ((size_t)((n) * 8 + (k)) * 64) * 8))

#define DB(n)                                                                  \
    long b##n##_0 = WB(n,0), b##n##_1 = WB(n,1), b##n##_2 = WB(n,2),           \
         b##n##_3 = WB(n,3), b##n##_4 = WB(n,4), b##n##_5 = WB(n,5),           \
         b##n##_6 = WB(n,6), b##n##_7 = WB(n,7);

// 16 independent MFMAs per k-step: dependency distance = 16 issues.
#define KSTEP(k)                                                               \
    c0  = M8(a##k, b0_##k,  c0);  c1  = M8(a##k, b1_##k,  c1);                 \
    c2  = M8(a##k, b2_##k,  c2);  c3  = M8(a##k, b3_##k,  c3);                 \
    c4  = M8(a##k, b4_##k,  c4);  c5  = M8(a##k, b5_##k,  c5);                 \
    c6  = M8(a##k, b6_##k,  c6);  c7  = M8(a##k, b7_##k,  c7);                 \
    c8  = M8(a##k, b8_##k,  c8);  c9  = M8(a##k, b9_##k,  c9);                 \
    c10 = M8(a##k, b10_##k, c10); c11 = M8(a##k, b11_##k, c11);                \
    c12 = M8(a##k, b12_##k, c12); c13 = M8(a##k, b13_##k, c13);                \
    c14 = M8(a##k, b14_##k, c14); c15 = M8(a##k, b15_##k, c15);

__global__ void __launch_bounds__(256, 1)
__attribute__((amdgpu_waves_per_eu(1, 1)))
k_recur(const unsigned char* __restrict__ Wh8, const _Float16* __restrict__ gx,
        float* __restrict__ out)
{
    const int b    = blockIdx.x;
    const int tid  = threadIdx.x;      // 0..255
    const int lane = tid & 63;
    const int w    = tid >> 6;         // wave: cols [256w,+256), units [64w,+64)

    __shared__ __align__(16) float act[1024];          // 4 KB, per-wave 256
    __shared__ __align__(8)  unsigned char hbufs[2][256];

    float* actw = act + w * 256;
    const unsigned char* Wp = Wh8 + ((size_t)(w * 16) * 8 * 64) * 8 + lane * 8;

    // ---- 128 register-resident fp8 B-fragments (256 regs) ----
    DB(0)  DB(1)  DB(2)  DB(3)  DB(4)  DB(5)  DB(6)  DB(7)
    DB(8)  DB(9)  DB(10) DB(11) DB(12) DB(13) DB(14) DB(15)

    hbufs[0][tid] = 0;                 // h0 = 0
    float s = 0.0f;
    const int u = w * 64 + lane;       // this thread's unit
    uint2 gcu = *(const uint2*)(gx + (size_t)b * G4 + 4 * u);  // a,i,f,o packed
    __syncthreads();

#pragma unroll 1
    for (int t = 0; t < T_STEPS; ++t) {
        // prefetch next-step gx: ONE 8B load (unit-major layout)
        uint2 gnx; gnx.x = 0u; gnx.y = 0u;
        if (t + 1 < T_STEPS) {
            gnx = *(const uint2*)(gx + ((size_t)(t + 1) * BATCH + b) * G4 + 4 * u);
        }

        // ---- A-fragments: fp8 h broadcast ----
        const unsigned char* hb = &hbufs[t & 1][0] + ((lane >> 4) * 8);
        long a0 = *(const long*)(hb + 0);
        long a1 = *(const long*)(hb + 32);
        long a2 = *(const long*)(hb + 64);
        long a3 = *(const long*)(hb + 96);
        long a4 = *(const long*)(hb + 128);
        long a5 = *(const long*)(hb + 160);
        long a6 = *(const long*)(hb + 192);
        long a7 = *(const long*)(hb + 224);

        f32x4 c0  = {0,0,0,0}, c1  = {0,0,0,0}, c2  = {0,0,0,0}, c3  = {0,0,0,0};
        f32x4 c4  = {0,0,0,0}, c5  = {0,0,0,0}, c6  = {0,0,0,0}, c7  = {0,0,0,0};
        f32x4 c8  = {0,0,0,0}, c9  = {0,0,0,0}, c10 = {0,0,0,0}, c11 = {0,0,0,0};
        f32x4 c12 = {0,0,0,0}, c13 = {0,0,0,0}, c14 = {0,0,0,0}, c15 = {0,0,0,0};

        KSTEP(0) KSTEP(1) KSTEP(2) KSTEP(3)
        KSTEP(4) KSTEP(5) KSTEP(6) KSTEP(7)

        // single store block: row 0 of each C tile (lanes 0..15)
        if (lane < 16) {
            actw[0  * 16 + lane] = c0[0];   actw[1  * 16 + lane] = c1[0];
            actw[2  * 16 + lane] = c2[0];   actw[3  * 16 + lane] = c3[0];
            actw[4  * 16 + lane] = c4[0];   actw[5  * 16 + lane] = c5[0];
            actw[6  * 16 + lane] = c6[0];   actw[7  * 16 + lane] = c7[0];
            actw[8  * 16 + lane] = c8[0];   actw[9  * 16 + lane] = c9[0];
            actw[10 * 16 + lane] = c10[0];  actw[11 * 16 + lane] = c11[0];
            actw[12 * 16 + lane] = c12[0];  actw[13 * 16 + lane] = c13[0];
            actw[14 * 16 + lane] = c14[0];  actw[15 * 16 + lane] = c15[0];
        }
        asm volatile("s_waitcnt lgkmcnt(0)" ::: "memory");  // act stores done

        // ---- epilogue: all 64 lanes/wave; unit u = 64w + lane ----
        {
            half2_t p01, p23;
            __builtin_memcpy(&p01, &gcu.x, 4);
            __builtin_memcpy(&p23, &gcu.y, 4);
            float4 g4v = ((const float4*)act)[w * 64 + lane];  // a,i,f,o raw
            const float S = 0.0009765625f;                     // 2^-10
            float gA = g4v.x * S + (float)p01.x;
            float gB = g4v.y * S + (float)p01.y;
            float gC = g4v.z * S + (float)p23.x;
            float gD = g4v.w * S + (float)p23.y;
            float aa = fast_tanh(gA);
            float ii = fast_sigmoid(gB);
            float ff = fast_sigmoid(gC);
            float oo = fast_sigmoid(gD);
            s = aa * ii + s * ff;
            float h = fast_tanh(s) * oo;
            out[((size_t)t * BATCH + b) * HID + u] = h;
            unsigned p8 = cvt2_fp8<false>(h * 16.0f, h * 16.0f, 0u);
            hbufs[(t + 1) & 1][u] = (unsigned char)(p8 & 0xffu);
        }
        gcu = gnx;
        __syncthreads();   // next slot complete before t+1 A-reads
    }
}

extern "C" void kernel_launch(void* const* d_in, const int* in_sizes, int n_in,
                              void* d_out, int out_size, void* d_ws, size_t ws_size,
                              hipStream_t stream) {
    const float* X   = (const float*)d_in[0];
    const float* Wax = (const float*)d_in[1];
    const float* Wix = (const float*)d_in[2];
    const float* Wfx = (const float*)d_in[3];
    const float* Wox = (const float*)d_in[4];
    const float* Wah = (const float*)d_in[5];
    const float* Wih = (const float*)d_in[6];
    const float* Wfh = (const float*)d_in[7];
    const float* Woh = (const float*)d_in[8];
    const float* ba  = (const float*)d_in[9];
    const float* bi  = (const float*)d_in[10];
    const float* bf  = (const float*)d_in[11];
    const float* bo  = (const float*)d_in[12];

    _Float16* ws  = (_Float16*)d_ws;
    _Float16* Xh  = ws + XH_OFF;
    _Float16* Wxt = ws + WXT_OFF;
    _Float16* gxp = ws + GX_OFF;
    unsigned char* Wh8 = (unsigned char*)d_ws + WH8_BYTE_OFF;

    k_prep_x<<<dim3(GM * 256 / 4 / 256), dim3(256), 0, stream>>>(X, Xh);
    k_prep_w<<<dim3(1024), dim3(256), 0, stream>>>(Wax, Wix, Wfx, Wox, Wxt);
    k_prep_wfrag8<<<dim3(128), dim3(256), 0, stream>>>(Wah, Wih, Wfh, Woh, Wh8);
    k_gemm<<<dim3(GM / 128, G4 / 64), dim3(256), 0, stream>>>(
        Xh, Wxt, ba, bi, bf, bo, gxp);
    k_recur<<<dim3(BATCH), dim3(256), 0, stream>>>(Wh8, gxp, (float*)d_out);
}

// Round 15
// 909.132 us; speedup vs baseline: 5.6516x; 1.0223x over previous
//
#include <hip/hip_runtime.h>
#include <hip/hip_fp16.h>

// LSTM T=512 B=64 D=256 H=256, fp32 in/out.
//
// Phase 0: X->f16; Wxt [4H][K] f16; Wh8 = Wh*64 quantized to fp8 e4m3 and
//          packed in MFMA B-fragment order, unit-major columns (c=4u+g).
// Phase 1: gx = X @ Wx + b via f16 MFMA GEMM -> ws f16 (unit-major store).
// Phase 2: recurrence, 1 CU/batch, 256 thr (4 waves, 1/SIMD).
//          R14 counters: VALUBusy excess ~1000cyc = 256 v_accvgpr_read x 2cyc
//          (all 128 B-frag longs in AGPR; compiler copies to VGPR per MFMA).
//          R15 fix: 12 B-tiles in regs (192 regs -> arch-VGPR-resident),
//          4 B-tiles streamed from LDS (16KB/wave, 4 ds_read_b64 per k-step,
//          conflict-free). Accumulators may go AGPR - free for MFMA C/D.

#define T_STEPS 512
#define BATCH   64
#define HID     256
#define G4      1024
#define GM      (T_STEPS * BATCH)     // 32768

typedef _Float16 half2_t __attribute__((ext_vector_type(2)));
typedef _Float16 f16x8   __attribute__((ext_vector_type(8)));
typedef float    f32x4   __attribute__((ext_vector_type(4)));

// ws layout
#define XH_OFF  0u          // f16[32768][256]
#define WXT_OFF 8388608u    // f16[1024][256]
#define GX_OFF  8912896u    // f16[32768][1024]
#define WH8_BYTE_OFF (8650752u * 2u)   // 256 KB fp8 frag-packed Wh

__device__ __forceinline__ float fast_sigmoid(float x) {
    return 1.0f / (1.0f + __expf(-x));
}
__device__ __forceinline__ float fast_tanh(float x) {
    return 2.0f / (1.0f + __expf(-2.0f * x)) - 1.0f;
}

// ---- fp8 e4m3fn encode (RN; flush |x|<2^-6 to 0; clamp to 448) ----
__device__ __forceinline__ unsigned char sw_e4m3(float x) {
    unsigned u = __float_as_uint(x);
    unsigned s = (u >> 24) & 0x80u;
    int e = (int)((u >> 23) & 0xffu) - 127;
    unsigned m = u & 0x7fffffu;
    if (e < -6) return (unsigned char)s;
    m += 0x00080000u;
    if (m & 0x800000u) { m = 0; e += 1; }
    int E = e + 7;
    if (E > 15 || (E == 15 && (m >> 20) > 6)) { E = 15; m = 6u << 20; }
    return (unsigned char)(s | ((unsigned)E << 3) | (m >> 20));
}
template <bool HI>
__device__ __forceinline__ unsigned cvt2_fp8(float a, float b, unsigned old) {
#if __has_builtin(__builtin_amdgcn_cvt_pk_fp8_f32)
    return (unsigned)__builtin_amdgcn_cvt_pk_fp8_f32(a, b, (int)old, HI);
#else
    unsigned lo16 = (unsigned)sw_e4m3(a) | ((unsigned)sw_e4m3(b) << 8);
    return HI ? ((old & 0xFFFFu) | (lo16 << 16))
              : ((old & 0xFFFF0000u) | lo16);
#endif
}

// ---------------- Phase 0a: X f32 -> f16 ----------------
__global__ __launch_bounds__(256) void k_prep_x(const float* __restrict__ X,
                                                _Float16* __restrict__ Xh) {
    const int i = blockIdx.x * 256 + threadIdx.x;
    float4 v = ((const float4*)X)[i];
    half2_t a; a.x = (_Float16)v.x; a.y = (_Float16)v.y;
    half2_t b; b.x = (_Float16)v.z; b.y = (_Float16)v.w;
    ((half2_t*)Xh)[2 * i]     = a;
    ((half2_t*)Xh)[2 * i + 1] = b;
}

// ---------------- Phase 0b: Wxt [4H][K] (gate-major cols) ----------------
__global__ __launch_bounds__(256) void k_prep_w(
    const float* __restrict__ Wax, const float* __restrict__ Wix,
    const float* __restrict__ Wfx, const float* __restrict__ Wox,
    _Float16* __restrict__ Wxt)
{
    const int id = blockIdx.x * 256 + threadIdx.x;
    const int k  = id >> 10;
    const int c  = id & 1023;
    const int g  = c >> 8;
    const int j  = c & 255;
    const float* src = (g == 0) ? Wax : (g == 1) ? Wix : (g == 2) ? Wfx : Wox;
    Wxt[c * 256 + k] = (_Float16)src[k * 256 + j];
}

// ---------------- Phase 0c: Wh8 fp8 fragments, unit-major cols -----------
__global__ __launch_bounds__(256) void k_prep_wfrag8(
    const float* __restrict__ Wah, const float* __restrict__ Wih,
    const float* __restrict__ Wfh, const float* __restrict__ Woh,
    unsigned char* __restrict__ Wh8)
{
    const int id  = blockIdx.x * 256 + threadIdx.x;   // [0, 32768)
    const int l   = id & 63;
    const int kt  = (id >> 6) & 7;
    const int ntG = id >> 9;
    const int c   = ntG * 16 + (l & 15);
    const int u   = c >> 2;
    const int g   = c & 3;
    const int k0  = kt * 32 + (l >> 4) * 8;
    const float* W = (g == 0) ? Wah : (g == 1) ? Wih : (g == 2) ? Wfh : Woh;
    float v[8];
#pragma unroll
    for (int e = 0; e < 8; ++e)
        v[e] = W[(size_t)(k0 + e) * 256 + u] * 64.0f;
    unsigned lo = cvt2_fp8<false>(v[0], v[1], 0u);
    lo = cvt2_fp8<true>(v[2], v[3], lo);
    unsigned hi = cvt2_fp8<false>(v[4], v[5], 0u);
    hi = cvt2_fp8<true>(v[6], v[7], hi);
    uint2 pk; pk.x = lo; pk.y = hi;
    *(uint2*)(Wh8 + ((size_t)(ntG * 8 + kt) * 64 + l) * 8) = pk;
}

// ---------------- Phase 1: gx = Xh @ Wxt^T + b (unit-major store) --------
__global__ __launch_bounds__(256) void k_gemm(const _Float16* __restrict__ Xh,
                                              const _Float16* __restrict__ Wxt,
                                              const float* __restrict__ ba,
                                              const float* __restrict__ bi,
                                              const float* __restrict__ bf_,
                                              const float* __restrict__ bo,
                                              _Float16* __restrict__ gx)
{
    const int lane = threadIdx.x & 63, wave = threadIdx.x >> 6;
    const int rowbase = blockIdx.x * 128 + wave * 32;
    const int colbase = blockIdx.y * 64;
    const int r15 = lane & 15, kg = lane >> 4;

    f32x4 acc[2][4] = {};
    const _Float16* ap0 = Xh  + (size_t)(rowbase + r15) * 256 + kg * 8;
    const _Float16* ap1 = ap0 + 16 * 256;
    const _Float16* bp  = Wxt + (size_t)(colbase + r15) * 256 + kg * 8;

#pragma unroll
    for (int ks = 0; ks < 8; ++ks) {
        f16x8 a0 = *(const f16x8*)(ap0 + ks * 32);
        f16x8 a1 = *(const f16x8*)(ap1 + ks * 32);
        f16x8 b0 = *(const f16x8*)(bp  + ks * 32);
        f16x8 b1 = *(const f16x8*)(bp  + 16 * 256 + ks * 32);
        f16x8 b2 = *(const f16x8*)(bp  + 32 * 256 + ks * 32);
        f16x8 b3 = *(const f16x8*)(bp  + 48 * 256 + ks * 32);
        acc[0][0] = __builtin_amdgcn_mfma_f32_16x16x32_f16(a0, b0, acc[0][0], 0, 0, 0);
        acc[0][1] = __builtin_amdgcn_mfma_f32_16x16x32_f16(a0, b1, acc[0][1], 0, 0, 0);
        acc[0][2] = __builtin_amdgcn_mfma_f32_16x16x32_f16(a0, b2, acc[0][2], 0, 0, 0);
        acc[0][3] = __builtin_amdgcn_mfma_f32_16x16x32_f16(a0, b3, acc[0][3], 0, 0, 0);
        acc[1][0] = __builtin_amdgcn_mfma_f32_16x16x32_f16(a1, b0, acc[1][0], 0, 0, 0);
        acc[1][1] = __builtin_amdgcn_mfma_f32_16x16x32_f16(a1, b1, acc[1][1], 0, 0, 0);
        acc[1][2] = __builtin_amdgcn_mfma_f32_16x16x32_f16(a1, b2, acc[1][2], 0, 0, 0);
        acc[1][3] = __builtin_amdgcn_mfma_f32_16x16x32_f16(a1, b3, acc[1][3], 0, 0, 0);
    }
    float bias_n[4];
#pragma unroll
    for (int nt = 0; nt < 4; ++nt) {
        int col = colbase + nt * 16 + r15;
        bias_n[nt] = (col < 256) ? ba[col]
                   : (col < 512) ? bi[col - 256]
                   : (col < 768) ? bf_[col - 512]
                                 : bo[col - 768];
    }
    // unit-major permuted store: col (= g*256+j) -> 4*j + g
#pragma unroll
    for (int mt = 0; mt < 2; ++mt)
#pragma unroll
        for (int nt = 0; nt < 4; ++nt)
#pragma unroll
            for (int r = 0; r < 4; ++r) {
                int row = rowbase + mt * 16 + kg * 4 + r;
                int col = colbase + nt * 16 + r15;
                int g   = col >> 8, j = col & 255;
                gx[(size_t)row * G4 + 4 * j + g] =
                    (_Float16)(acc[mt][nt][r] + bias_n[nt]);
            }
}

// ---------------- Phase 2: fp8 MFMA recurrence ----------------
// 12 reg-tiles + 4 LDS-tiles; k-major interleave (16 indep MFMAs per k).

#define M8(a, bfr, acc) \
    __builtin_amdgcn_mfma_f32_16x16x32_fp8_fp8((a), (bfr), (acc), 0, 0, 0)
#define WB(n, k) (*(const long*)(Wp + ((size_t)((n) * 8 + (k)) * 64) * 8))

#define DB(n)                                                                  \
    long b##n##_0 = WB(n,0), b##n##_1 = WB(n,1), b##n##_2 = WB(n,2),           \
         b##n##_3 = WB(n,3), b##n##_4 = WB(n,4), b##n##_5 = WB(n,5),           \
         b##n##_6 = WB(n,6), b##n##_7 = WB(n,7);

// k-step: 4 LDS b64 loads (tiles 12..15) + 16 independent MFMAs
#define KBLOCK(k)                                                              \
  {                                                                            \
    long l12 = *(const long*)(wlw + (0 * 8 + (k)) * 512);                      \
    long l13 = *(const long*)(wlw + (1 * 8 + (k)) * 512);                      \
    long l14 = *(const long*)(wlw + (2 * 8 + (k)) * 512);                      \
    long l15 = *(const long*)(wlw + (3 * 8 + (k)) * 512);                      \
    c0  = M8(a##k, b0_##k,  c0);  c1  = M8(a##k, b1_##k,  c1);                 \
    c2  = M8(a##k, b2_##k,  c2);  c3  = M8(a##k, b3_##k,  c3);                 \
    c4  = M8(a##k, b4_##k,  c4);  c5  = M8(a##k, b5_##k,  c5);                 \
    c6  = M8(a##k, b6_##k,  c6);  c7  = M8(a##k, b7_##k,  c7);                 \
    c8  = M8(a##k, b8_##k,  c8);  c9  = M8(a##k, b9_##k,  c9);                 \
    c10 = M8(a##k, b10_##k, c10); c11 = M8(a##k, b11_##k, c11);                \
    c12 = M8(a##k, l12, c12);     c13 = M8(a##k, l13, c13);                    \
    c14 = M8(a##k, l14, c14);     c15 = M8(a##k, l15, c15);                    \
  }

__global__ void __launch_bounds__(256, 1)
__attribute__((amdgpu_waves_per_eu(1, 1)))
k_recur(const unsigned char* __restrict__ Wh8, const _Float16* __restrict__ gx,
        float* __restrict__ out)
{
    const int b    = blockIdx.x;
    const int tid  = threadIdx.x;      // 0..255
    const int lane = tid & 63;
    const int w    = tid >> 6;         // wave: cols [256w,+256), units [64w,+64)

    __shared__ __align__(16) unsigned char wl8[4 * 16384];   // 64 KB: 4 tiles/wave
    __shared__ __align__(16) float act[1024];                // 4 KB
    __shared__ __align__(8)  unsigned char hbufs[2][256];

    float* actw = act + w * 256;
    const unsigned char* Wp = Wh8 + ((size_t)(w * 16) * 8 * 64) * 8 + lane * 8;

    // ---- 12 register-resident B-tiles (96 longs = 192 regs, arch VGPRs) ----
    DB(0)  DB(1)  DB(2)  DB(3)  DB(4)  DB(5)
    DB(6)  DB(7)  DB(8)  DB(9)  DB(10) DB(11)

    // ---- tiles 12..15 -> LDS (per-wave 16 KB, lane-contiguous) ----
    unsigned char* wlw = wl8 + w * 16384 + lane * 8;
#pragma unroll
    for (int j = 0; j < 4; ++j)
#pragma unroll
        for (int k = 0; k < 8; ++k)
            *(long*)(wlw + (j * 8 + k) * 512) = WB(12 + j, k);

    hbufs[0][tid] = 0;                 // h0 = 0
    float s = 0.0f;
    const int u = w * 64 + lane;       // this thread's unit
    uint2 gcu = *(const uint2*)(gx + (size_t)b * G4 + 4 * u);  // a,i,f,o packed
    __syncthreads();

#pragma unroll 1
    for (int t = 0; t < T_STEPS; ++t) {
        // prefetch next-step gx: ONE 8B load (unit-major layout)
        uint2 gnx; gnx.x = 0u; gnx.y = 0u;
        if (t + 1 < T_STEPS) {
            gnx = *(const uint2*)(gx + ((size_t)(t + 1) * BATCH + b) * G4 + 4 * u);
        }

        // ---- A-fragments: fp8 h broadcast ----
        const unsigned char* hb = &hbufs[t & 1][0] + ((lane >> 4) * 8);
        long a0 = *(const long*)(hb + 0);
        long a1 = *(const long*)(hb + 32);
        long a2 = *(const long*)(hb + 64);
        long a3 = *(const long*)(hb + 96);
        long a4 = *(const long*)(hb + 128);
        long a5 = *(const long*)(hb + 160);
        long a6 = *(const long*)(hb + 192);
        long a7 = *(const long*)(hb + 224);

        f32x4 c0  = {0,0,0,0}, c1  = {0,0,0,0}, c2  = {0,0,0,0}, c3  = {0,0,0,0};
        f32x4 c4  = {0,0,0,0}, c5  = {0,0,0,0}, c6  = {0,0,0,0}, c7  = {0,0,0,0};
        f32x4 c8  = {0,0,0,0}, c9  = {0,0,0,0}, c10 = {0,0,0,0}, c11 = {0,0,0,0};
        f32x4 c12 = {0,0,0,0}, c13 = {0,0,0,0}, c14 = {0,0,0,0}, c15 = {0,0,0,0};

        KBLOCK(0) KBLOCK(1) KBLOCK(2) KBLOCK(3)
        KBLOCK(4) KBLOCK(5) KBLOCK(6) KBLOCK(7)

        // single store block: row 0 of each C tile (lanes 0..15)
        if (lane < 16) {
            actw[0  * 16 + lane] = c0[0];   actw[1  * 16 + lane] = c1[0];
            actw[2  * 16 + lane] = c2[0];   actw[3  * 16 + lane] = c3[0];
            actw[4  * 16 + lane] = c4[0];   actw[5  * 16 + lane] = c5[0];
            actw[6  * 16 + lane] = c6[0];   actw[7  * 16 + lane] = c7[0];
            actw[8  * 16 + lane] = c8[0];   actw[9  * 16 + lane] = c9[0];
            actw[10 * 16 + lane] = c10[0];  actw[11 * 16 + lane] = c11[0];
            actw[12 * 16 + lane] = c12[0];  actw[13 * 16 + lane] = c13[0];
            actw[14 * 16 + lane] = c14[0];  actw[15 * 16 + lane] = c15[0];
        }
        asm volatile("s_waitcnt lgkmcnt(0)" ::: "memory");  // act stores done

        // ---- epilogue: all 64 lanes/wave; unit u = 64w + lane ----
        {
            half2_t p01, p23;
            __builtin_memcpy(&p01, &gcu.x, 4);
            __builtin_memcpy(&p23, &gcu.y, 4);
            float4 g4v = ((const float4*)act)[w * 64 + lane];  // a,i,f,o raw
            const float S = 0.0009765625f;                     // 2^-10
            float gA = g4v.x * S + (float)p01.x;
            float gB = g4v.y * S + (float)p01.y;
            float gC = g4v.z * S + (float)p23.x;
            float gD = g4v.w * S + (float)p23.y;
            float aa = fast_tanh(gA);
            float ii = fast_sigmoid(gB);
            float ff = fast_sigmoid(gC);
            float oo = fast_sigmoid(gD);
            s = aa * ii + s * ff;
            float h = fast_tanh(s) * oo;
            out[((size_t)t * BATCH + b) * HID + u] = h;
            unsigned p8 = cvt2_fp8<false>(h * 16.0f, h * 16.0f, 0u);
            hbufs[(t + 1) & 1][u] = (unsigned char)(p8 & 0xffu);
        }
        gcu = gnx;
        __syncthreads();   // next slot complete before t+1 A-reads
    }
}

extern "C" void kernel_launch(void* const* d_in, const int* in_sizes, int n_in,
                              void* d_out, int out_size, void* d_ws, size_t ws_size,
                              hipStream_t stream) {
    const float* X   = (const float*)d_in[0];
    const float* Wax = (const float*)d_in[1];
    const float* Wix = (const float*)d_in[2];
    const float* Wfx = (const float*)d_in[3];
    const float* Wox = (const float*)d_in[4];
    const float* Wah = (const float*)d_in[5];
    const float* Wih = (const float*)d_in[6];
    const float* Wfh = (const float*)d_in[7];
    const float* Woh = (const float*)d_in[8];
    const float* ba  = (const float*)d_in[9];
    const float* bi  = (const float*)d_in[10];
    const float* bf  = (const float*)d_in[11];
    const float* bo  = (const float*)d_in[12];

    _Float16* ws  = (_Float16*)d_ws;
    _Float16* Xh  = ws + XH_OFF;
    _Float16* Wxt = ws + WXT_OFF;
    _Float16* gxp = ws + GX_OFF;
    unsigned char* Wh8 = (unsigned char*)d_ws + WH8_BYTE_OFF;

    k_prep_x<<<dim3(GM * 256 / 4 / 256), dim3(256), 0, stream>>>(X, Xh);
    k_prep_w<<<dim3(1024), dim3(256), 0, stream>>>(Wax, Wix, Wfx, Wox, Wxt);
    k_prep_wfrag8<<<dim3(128), dim3(256), 0, stream>>>(Wah, Wih, Wfh, Woh, Wh8);
    k_gemm<<<dim3(GM / 128, G4 / 64), dim3(256), 0, stream>>>(
        Xh, Wxt, ba, bi, bf, bo, gxp);
    k_recur<<<dim3(BATCH), dim3(256), 0, stream>>>(Wh8, gxp, (float*)d_out);
}

// Round 16
// 846.512 us; speedup vs baseline: 6.0696x; 1.0740x over previous
//
#include <hip/hip_runtime.h>
#include <hip/hip_fp16.h>

// LSTM T=512 B=64 D=256 H=256, fp32 in/out.
//
// Phase 0: X->f16; Wxt [4H][K] f16; Wh8 = Wh*64 quantized to fp8 e4m3 and
//          packed in MFMA B-fragment order, unit-major columns (c=4u+g).
// Phase 1: gx = X @ Wx + b via f16 MFMA GEMM -> ws f16 (unit-major store).
// Phase 2: recurrence, 1 CU/batch, 512 thr (8 waves, 2/SIMD -> TLP).
//          R15 counters: at 1 wave/SIMD the 192-reg weight set broke the 256
//          arch-VGPR cap -> AGPR moves, and MFMA/VALU/DS phases serialized.
//          R16: each wave owns 8 N-tiles = 64 longs = 128 regs -> ~195 total,
//          fully arch-VGPR under the 2-wave/SIMD budget (no AGPR moves by
//          construction); whole Wh8 still register-resident per CU (8x32KB).
//          2 waves/SIMD overlap epilogue VALU with MFMA issue.

#define T_STEPS 512
#define BATCH   64
#define HID     256
#define G4      1024
#define GM      (T_STEPS * BATCH)     // 32768

typedef _Float16 half2_t __attribute__((ext_vector_type(2)));
typedef _Float16 f16x8   __attribute__((ext_vector_type(8)));
typedef float    f32x4   __attribute__((ext_vector_type(4)));

// ws layout
#define XH_OFF  0u          // f16[32768][256]
#define WXT_OFF 8388608u    // f16[1024][256]
#define GX_OFF  8912896u    // f16[32768][1024]
#define WH8_BYTE_OFF (8650752u * 2u)   // 256 KB fp8 frag-packed Wh

__device__ __forceinline__ float fast_sigmoid(float x) {
    return 1.0f / (1.0f + __expf(-x));
}
__device__ __forceinline__ float fast_tanh(float x) {
    return 2.0f / (1.0f + __expf(-2.0f * x)) - 1.0f;
}

// ---- fp8 e4m3fn encode (RN; flush |x|<2^-6 to 0; clamp to 448) ----
__device__ __forceinline__ unsigned char sw_e4m3(float x) {
    unsigned u = __float_as_uint(x);
    unsigned s = (u >> 24) & 0x80u;
    int e = (int)((u >> 23) & 0xffu) - 127;
    unsigned m = u & 0x7fffffu;
    if (e < -6) return (unsigned char)s;
    m += 0x00080000u;
    if (m & 0x800000u) { m = 0; e += 1; }
    int E = e + 7;
    if (E > 15 || (E == 15 && (m >> 20) > 6)) { E = 15; m = 6u << 20; }
    return (unsigned char)(s | ((unsigned)E << 3) | (m >> 20));
}
template <bool HI>
__device__ __forceinline__ unsigned cvt2_fp8(float a, float b, unsigned old) {
#if __has_builtin(__builtin_amdgcn_cvt_pk_fp8_f32)
    return (unsigned)__builtin_amdgcn_cvt_pk_fp8_f32(a, b, (int)old, HI);
#else
    unsigned lo16 = (unsigned)sw_e4m3(a) | ((unsigned)sw_e4m3(b) << 8);
    return HI ? ((old & 0xFFFFu) | (lo16 << 16))
              : ((old & 0xFFFF0000u) | lo16);
#endif
}

// ---------------- Phase 0a: X f32 -> f16 ----------------
__global__ __launch_bounds__(256) void k_prep_x(const float* __restrict__ X,
                                                _Float16* __restrict__ Xh) {
    const int i = blockIdx.x * 256 + threadIdx.x;
    float4 v = ((const float4*)X)[i];
    half2_t a; a.x = (_Float16)v.x; a.y = (_Float16)v.y;
    half2_t b; b.x = (_Float16)v.z; b.y = (_Float16)v.w;
    ((half2_t*)Xh)[2 * i]     = a;
    ((half2_t*)Xh)[2 * i + 1] = b;
}

// ---------------- Phase 0b: Wxt [4H][K] (gate-major cols) ----------------
__global__ __launch_bounds__(256) void k_prep_w(
    const float* __restrict__ Wax, const float* __restrict__ Wix,
    const float* __restrict__ Wfx, const float* __restrict__ Wox,
    _Float16* __restrict__ Wxt)
{
    const int id = blockIdx.x * 256 + threadIdx.x;
    const int k  = id >> 10;
    const int c  = id & 1023;
    const int g  = c >> 8;
    const int j  = c & 255;
    const float* src = (g == 0) ? Wax : (g == 1) ? Wix : (g == 2) ? Wfx : Wox;
    Wxt[c * 256 + k] = (_Float16)src[k * 256 + j];
}

// ---------------- Phase 0c: Wh8 fp8 fragments, unit-major cols -----------
__global__ __launch_bounds__(256) void k_prep_wfrag8(
    const float* __restrict__ Wah, const float* __restrict__ Wih,
    const float* __restrict__ Wfh, const float* __restrict__ Woh,
    unsigned char* __restrict__ Wh8)
{
    const int id  = blockIdx.x * 256 + threadIdx.x;   // [0, 32768)
    const int l   = id & 63;
    const int kt  = (id >> 6) & 7;
    const int ntG = id >> 9;
    const int c   = ntG * 16 + (l & 15);
    const int u   = c >> 2;
    const int g   = c & 3;
    const int k0  = kt * 32 + (l >> 4) * 8;
    const float* W = (g == 0) ? Wah : (g == 1) ? Wih : (g == 2) ? Wfh : Woh;
    float v[8];
#pragma unroll
    for (int e = 0; e < 8; ++e)
        v[e] = W[(size_t)(k0 + e) * 256 + u] * 64.0f;
    unsigned lo = cvt2_fp8<false>(v[0], v[1], 0u);
    lo = cvt2_fp8<true>(v[2], v[3], lo);
    unsigned hi = cvt2_fp8<false>(v[4], v[5], 0u);
    hi = cvt2_fp8<true>(v[6], v[7], hi);
    uint2 pk; pk.x = lo; pk.y = hi;
    *(uint2*)(Wh8 + ((size_t)(ntG * 8 + kt) * 64 + l) * 8) = pk;
}

// ---------------- Phase 1: gx = Xh @ Wxt^T + b (unit-major store) --------
__global__ __launch_bounds__(256) void k_gemm(const _Float16* __restrict__ Xh,
                                              const _Float16* __restrict__ Wxt,
                                              const float* __restrict__ ba,
                                              const float* __restrict__ bi,
                                              const float* __restrict__ bf_,
                                              const float* __restrict__ bo,
                                              _Float16* __restrict__ gx)
{
    const int lane = threadIdx.x & 63, wave = threadIdx.x >> 6;
    const int rowbase = blockIdx.x * 128 + wave * 32;
    const int colbase = blockIdx.y * 64;
    const int r15 = lane & 15, kg = lane >> 4;

    f32x4 acc[2][4] = {};
    const _Float16* ap0 = Xh  + (size_t)(rowbase + r15) * 256 + kg * 8;
    const _Float16* ap1 = ap0 + 16 * 256;
    const _Float16* bp  = Wxt + (size_t)(colbase + r15) * 256 + kg * 8;

#pragma unroll
    for (int ks = 0; ks < 8; ++ks) {
        f16x8 a0 = *(const f16x8*)(ap0 + ks * 32);
        f16x8 a1 = *(const f16x8*)(ap1 + ks * 32);
        f16x8 b0 = *(const f16x8*)(bp  + ks * 32);
        f16x8 b1 = *(const f16x8*)(bp  + 16 * 256 + ks * 32);
        f16x8 b2 = *(const f16x8*)(bp  + 32 * 256 + ks * 32);
        f16x8 b3 = *(const f16x8*)(bp  + 48 * 256 + ks * 32);
        acc[0][0] = __builtin_amdgcn_mfma_f32_16x16x32_f16(a0, b0, acc[0][0], 0, 0, 0);
        acc[0][1] = __builtin_amdgcn_mfma_f32_16x16x32_f16(a0, b1, acc[0][1], 0, 0, 0);
        acc[0][2] = __builtin_amdgcn_mfma_f32_16x16x32_f16(a0, b2, acc[0][2], 0, 0, 0);
        acc[0][3] = __builtin_amdgcn_mfma_f32_16x16x32_f16(a0, b3, acc[0][3], 0, 0, 0);
        acc[1][0] = __builtin_amdgcn_mfma_f32_16x16x32_f16(a1, b0, acc[1][0], 0, 0, 0);
        acc[1][1] = __builtin_amdgcn_mfma_f32_16x16x32_f16(a1, b1, acc[1][1], 0, 0, 0);
        acc[1][2] = __builtin_amdgcn_mfma_f32_16x16x32_f16(a1, b2, acc[1][2], 0, 0, 0);
        acc[1][3] = __builtin_amdgcn_mfma_f32_16x16x32_f16(a1, b3, acc[1][3], 0, 0, 0);
    }
    float bias_n[4];
#pragma unroll
    for (int nt = 0; nt < 4; ++nt) {
        int col = colbase + nt * 16 + r15;
        bias_n[nt] = (col < 256) ? ba[col]
                   : (col < 512) ? bi[col - 256]
                   : (col < 768) ? bf_[col - 512]
                                 : bo[col - 768];
    }
    // unit-major permuted store: col (= g*256+j) -> 4*j + g
#pragma unroll
    for (int mt = 0; mt < 2; ++mt)
#pragma unroll
        for (int nt = 0; nt < 4; ++nt)
#pragma unroll
            for (int r = 0; r < 4; ++r) {
                int row = rowbase + mt * 16 + kg * 4 + r;
                int col = colbase + nt * 16 + r15;
                int g   = col >> 8, j = col & 255;
                gx[(size_t)row * G4 + 4 * j + g] =
                    (_Float16)(acc[mt][nt][r] + bias_n[nt]);
            }
}

// ---------------- Phase 2: fp8 MFMA recurrence (8 waves, 2/SIMD) ---------

#define M8(a, bfr, acc) \
    __builtin_amdgcn_mfma_f32_16x16x32_fp8_fp8((a), (bfr), (acc), 0, 0, 0)
#define WB(n, k) (*(const long*)(Wp + ((size_t)((n) * 8 + (k)) * 64) * 8))

#define DB(n)                                                                  \
    long b##n##_0 = WB(n,0), b##n##_1 = WB(n,1), b##n##_2 = WB(n,2),           \
         b##n##_3 = WB(n,3), b##n##_4 = WB(n,4), b##n##_5 = WB(n,5),           \
         b##n##_6 = WB(n,6), b##n##_7 = WB(n,7);

// 8 independent MFMAs per k-step (one per owned tile)
#define KSTEP(k)                                                               \
    c0 = M8(a##k, b0_##k, c0);  c1 = M8(a##k, b1_##k, c1);                     \
    c2 = M8(a##k, b2_##k, c2);  c3 = M8(a##k, b3_##k, c3);                     \
    c4 = M8(a##k, b4_##k, c4);  c5 = M8(a##k, b5_##k, c5);                     \
    c6 = M8(a##k, b6_##k, c6);  c7 = M8(a##k, b7_##k, c7);

__global__ void __launch_bounds__(512, 1)
__attribute__((amdgpu_waves_per_eu(2, 2)))
k_recur(const unsigned char* __restrict__ Wh8, const _Float16* __restrict__ gx,
        float* __restrict__ out)
{
    const int b    = blockIdx.x;
    const int tid  = threadIdx.x;      // 0..511
    const int lane = tid & 63;
    const int w    = tid >> 6;         // wave 0..7: ntiles [8w, 8w+8)

    __shared__ __align__(16) float act[1024];          // 4 KB
    __shared__ __align__(8)  unsigned char hbufs[2][256];

    const unsigned char* Wp = Wh8 + ((size_t)(w * 8) * 8 * 64) * 8 + lane * 8;

    // ---- 64 register-resident fp8 B-fragment longs (128 arch VGPRs) ----
    DB(0) DB(1) DB(2) DB(3) DB(4) DB(5) DB(6) DB(7)

    if (tid < 256) hbufs[0][tid] = 0;  // h0 = 0
    float s = 0.0f;
    uint2 gcu; gcu.x = 0u; gcu.y = 0u;
    if (tid < 256)
        gcu = *(const uint2*)(gx + (size_t)b * G4 + 4 * tid);  // a,i,f,o packed
    __syncthreads();

#pragma unroll 1
    for (int t = 0; t < T_STEPS; ++t) {
        // prefetch next-step gx: ONE 8B load (unit-major layout)
        uint2 gnx; gnx.x = 0u; gnx.y = 0u;
        if (tid < 256 && t + 1 < T_STEPS) {
            gnx = *(const uint2*)(gx + ((size_t)(t + 1) * BATCH + b) * G4 + 4 * tid);
        }

        // ---- A-fragments: fp8 h broadcast ----
        const unsigned char* hb = &hbufs[t & 1][0] + ((lane >> 4) * 8);
        long a0 = *(const long*)(hb + 0);
        long a1 = *(const long*)(hb + 32);
        long a2 = *(const long*)(hb + 64);
        long a3 = *(const long*)(hb + 96);
        long a4 = *(const long*)(hb + 128);
        long a5 = *(const long*)(hb + 160);
        long a6 = *(const long*)(hb + 192);
        long a7 = *(const long*)(hb + 224);

        f32x4 c0 = {0,0,0,0}, c1 = {0,0,0,0}, c2 = {0,0,0,0}, c3 = {0,0,0,0};
        f32x4 c4 = {0,0,0,0}, c5 = {0,0,0,0}, c6 = {0,0,0,0}, c7 = {0,0,0,0};

        KSTEP(0) KSTEP(1) KSTEP(2) KSTEP(3)
        KSTEP(4) KSTEP(5) KSTEP(6) KSTEP(7)

        // store row 0 of each owned C tile (lanes 0..15); global tile = 8w+n
        if (lane < 16) {
            act[(w * 8 + 0) * 16 + lane] = c0[0];
            act[(w * 8 + 1) * 16 + lane] = c1[0];
            act[(w * 8 + 2) * 16 + lane] = c2[0];
            act[(w * 8 + 3) * 16 + lane] = c3[0];
            act[(w * 8 + 4) * 16 + lane] = c4[0];
            act[(w * 8 + 5) * 16 + lane] = c5[0];
            act[(w * 8 + 6) * 16 + lane] = c6[0];
            act[(w * 8 + 7) * 16 + lane] = c7[0];
        }
        __syncthreads();   // act complete (cross-wave) + hbuf reads done

        // ---- epilogue: threads 0..255, unit u = tid ----
        if (tid < 256) {
            half2_t p01, p23;
            __builtin_memcpy(&p01, &gcu.x, 4);
            __builtin_memcpy(&p23, &gcu.y, 4);
            float4 g4v = ((const float4*)act)[tid];            // a,i,f,o raw
            const float S = 0.0009765625f;                     // 2^-10
            float gA = g4v.x * S + (float)p01.x;
            float gB = g4v.y * S + (float)p01.y;
            float gC = g4v.z * S + (float)p23.x;
            float gD = g4v.w * S + (float)p23.y;
            float aa = fast_tanh(gA);
            float ii = fast_sigmoid(gB);
            float ff = fast_sigmoid(gC);
            float oo = fast_sigmoid(gD);
            s = aa * ii + s * ff;
            float h = fast_tanh(s) * oo;
            out[((size_t)t * BATCH + b) * HID + tid] = h;
            unsigned p8 = cvt2_fp8<false>(h * 16.0f, h * 16.0f, 0u);
            hbufs[(t + 1) & 1][tid] = (unsigned char)(p8 & 0xffu);
        }
        gcu = gnx;
        __syncthreads();   // next slot complete before t+1 A-reads
    }
}

extern "C" void kernel_launch(void* const* d_in, const int* in_sizes, int n_in,
                              void* d_out, int out_size, void* d_ws, size_t ws_size,
                              hipStream_t stream) {
    const float* X   = (const float*)d_in[0];
    const float* Wax = (const float*)d_in[1];
    const float* Wix = (const float*)d_in[2];
    const float* Wfx = (const float*)d_in[3];
    const float* Wox = (const float*)d_in[4];
    const float* Wah = (const float*)d_in[5];
    const float* Wih = (const float*)d_in[6];
    const float* Wfh = (const float*)d_in[7];
    const float* Woh = (const float*)d_in[8];
    const float* ba  = (const float*)d_in[9];
    const float* bi  = (const float*)d_in[10];
    const float* bf  = (const float*)d_in[11];
    const float* bo  = (const float*)d_in[12];

    _Float16* ws  = (_Float16*)d_ws;
    _Float16* Xh  = ws + XH_OFF;
    _Float16* Wxt = ws + WXT_OFF;
    _Float16* gxp = ws + GX_OFF;
    unsigned char* Wh8 = (unsigned char*)d_ws + WH8_BYTE_OFF;

    k_prep_x<<<dim3(GM * 256 / 4 / 256), dim3(256), 0, stream>>>(X, Xh);
    k_prep_w<<<dim3(1024), dim3(256), 0, stream>>>(Wax, Wix, Wfx, Wox, Wxt);
    k_prep_wfrag8<<<dim3(128), dim3(256), 0, stream>>>(Wah, Wih, Wfh, Woh, Wh8);
    k_gemm<<<dim3(GM / 128, G4 / 64), dim3(256), 0, stream>>>(
        Xh, Wxt, ba, bi, bf, bo, gxp);
    k_recur<<<dim3(BATCH), dim3(512), 0, stream>>>(Wh8, gxp, (float*)d_out);
}